// Round 2
// baseline (233.131 us; speedup 1.0000x reference)
//
#include <hip/hip_runtime.h>

// Problem dims (hardcoded from reference)
#define T_STEPS 256
#define B_ROWS  16384
#define IN_DIM  1024
#define C_CLS   10

typedef float vfloat4 __attribute__((ext_vector_type(4)));

// ---------------------------------------------------------------------------
// Kernel 1: xW = x @ W^T   ([B,IN] @ [C,IN]^T -> [B,C])
// Quarter-wave mapping: each 16-lane quarter owns ONE row; a 256-thread block
// covers 16 rows. x loads: per wave, 4 x 256B contiguous chunks = 16 cache
// lines per instruction (same as full coalescing). W (40 KB) is L1-resident.
// Reduction: only 4 shuffle steps (xor 8,4,2,1) per class -> 40 DS ops/thread
// vs 240 in the previous full-wave butterfly version.
// ---------------------------------------------------------------------------
__global__ __launch_bounds__(256) void gemv_kernel(
    const float4* __restrict__ x4,   // [B][256] float4 view of x
    const float4* __restrict__ W4,   // [C][256] float4 view of W
    float* __restrict__ xw)          // [B][C]
{
    const int tid  = threadIdx.x;
    const int wave = tid >> 6;
    const int lane = tid & 63;
    const int sub  = lane >> 4;       // which row of the wave's 4
    const int ql   = lane & 15;       // lane within the 16-lane quarter
    const int row  = blockIdx.x * 16 + wave * 4 + sub;

    float acc[C_CLS];
#pragma unroll
    for (int c = 0; c < C_CLS; ++c) acc[c] = 0.0f;

    const float4* __restrict__ xrow = x4 + (size_t)row * 256;

#pragma unroll 4
    for (int p = 0; p < 16; ++p) {
        float4 xv = xrow[p * 16 + ql];
#pragma unroll
        for (int c = 0; c < C_CLS; ++c) {
            float4 w = W4[c * 256 + p * 16 + ql];   // broadcast across quarters
            acc[c] = fmaf(xv.x, w.x,
                     fmaf(xv.y, w.y,
                     fmaf(xv.z, w.z,
                     fmaf(xv.w, w.w, acc[c]))));
        }
    }

    // reduce across the 16 lanes of this quarter (xor 8,4,2,1 stay in-quarter)
#pragma unroll
    for (int c = 0; c < C_CLS; ++c) {
        float v = acc[c];
#pragma unroll
        for (int off = 8; off >= 1; off >>= 1)
            v += __shfl_xor(v, off, 64);
        acc[c] = v;
    }

    if (ql == 0) {
#pragma unroll
        for (int c = 0; c < C_CLS; ++c)
            xw[row * C_CLS + c] = acc[c];
    }
}

// ---------------------------------------------------------------------------
// Kernel 2: out[t,b,c] = coef(t) * xW[b,c]
//   coef(t) = 5 - 9*0.9^(t+1) + 4*0.8^(t+1)   (closed form of the LI scan)
// Grid = 160 r4-chunks x 16 t-chunks. Each thread owns one float4 of xW
// (loaded ONCE) and streams 16 timesteps with a multiplicative coef
// recurrence: hot loop = 2 FMA + 4 mul + 1 nontemporal store. Per t, each
// block writes 4 KB contiguous -> fully coalesced streaming writes.
// ---------------------------------------------------------------------------
#define T_CHUNK 16
__global__ __launch_bounds__(256) void expand_kernel(
    const float4* __restrict__ xw4,  // B*C/4 = 40960 float4
    float4* __restrict__ out4)       // T*B*C/4 float4
{
    const int SLICE4 = (B_ROWS * C_CLS) / 4;   // 40960 float4 per timestep
    const int NR     = SLICE4 / 256;           // 160 r4-chunks

    const int rblk = blockIdx.x % NR;
    const int tblk = blockIdx.x / NR;
    const int r4   = rblk * 256 + threadIdx.x;
    const int t0   = tblk * T_CHUNK;

    const float L9 = -0.15200309344504995f;    // log2(0.9)
    const float L8 = -0.32192809488736235f;    // log2(0.8)

    float4 v = xw4[r4];
    float p9 = exp2f((float)(t0 + 1) * L9);    // 0.9^(t0+1)
    float p8 = exp2f((float)(t0 + 1) * L8);    // 0.8^(t0+1)

    float4* dst = out4 + (size_t)t0 * SLICE4 + r4;
#pragma unroll
    for (int i = 0; i < T_CHUNK; ++i) {
        float coef = fmaf(-9.0f, p9, fmaf(4.0f, p8, 5.0f));
        vfloat4 o;
        o.x = v.x * coef; o.y = v.y * coef; o.z = v.z * coef; o.w = v.w * coef;
        __builtin_nontemporal_store(o, (vfloat4*)dst);
        dst += SLICE4;
        p9 *= 0.9f;
        p8 *= 0.8f;
    }
}

extern "C" void kernel_launch(void* const* d_in, const int* in_sizes, int n_in,
                              void* d_out, int out_size, void* d_ws, size_t ws_size,
                              hipStream_t stream) {
    const float* x = (const float*)d_in[0];   // [B, IN] f32
    const float* W = (const float*)d_in[1];   // [C, IN] f32
    float* out = (float*)d_out;               // [T, B, C] f32
    float* xw  = (float*)d_ws;                // [B, C] f32 scratch (655 KB)

    gemv_kernel<<<B_ROWS / 16, 256, 0, stream>>>(
        (const float4*)x, (const float4*)W, xw);

    expand_kernel<<<(T_STEPS / T_CHUNK) * ((B_ROWS * C_CLS) / 4 / 256), 256, 0, stream>>>(
        (const float4*)xw, (float4*)out);
}